// Round 21
// baseline (70.585 us; speedup 1.0000x reference)
//
#include <hip/hip_runtime.h>
#include <stdint.h>

#define BB 8
#define NN 2048
#define IND 10
#define QK 32

typedef float f32x4 __attribute__((ext_vector_type(4)));

// Kernel 1: q[b][n][qd] = sum_d s[b,n,d]*Wq[qd,d]; k likewise.
// kt permuted for kernel 2's read: attn thread (wave w, lane i) owns cols
//   {512w + 4i + j : j=0..3} and {512w + 256 + 4i + j : j=0..3}.
// kt float4 index: (b*4+w)*4096 + (ev*8+jc)*64 + i, component c (qd=4ev+c).
__global__ __launch_bounds__(256) void qk_kernel(
    const float* __restrict__ s,
    const float* __restrict__ Wq, const float* __restrict__ Wk,
    float* __restrict__ q_ws, float* __restrict__ kt_ws) {
  int t = blockIdx.x * 256 + threadIdx.x;      // 0 .. B*N*QK-1 (exact)
  int b  = t >> 16;                            // N*QK = 65536
  int n  = (t >> 5) & (NN - 1);
  int qd = t & 31;
  const float* srow = s + (size_t)(b * NN + n) * IND;
  float acq = 0.f, ack = 0.f;
#pragma unroll
  for (int d = 0; d < IND; ++d) {
    float sv = srow[d];
    acq = fmaf(sv, Wq[qd * IND + d], acq);
    ack = fmaf(sv, Wk[qd * IND + d], ack);
  }
  q_ws[(size_t)(b * NN + n) * QK + qd] = acq;
  int w  = n >> 9;                 // wave (512 cols each)
  int m  = n & 511;
  int i  = (m & 255) >> 2;         // lane
  int jc = ((m < 256) ? 0 : 4) + (m & 3);
  int ev = qd >> 2, c = qd & 3;
  kt_ws[(((size_t)(b * 4 + w) * 4096) + (ev * 8 + jc) * 64 + i) * 4 + c] = ack;
}

// async global->LDS: lane's 16B from per-lane src -> uniform LDS base + lane*16
__device__ __forceinline__ void gload_lds16(const float* src, float* lds_dst) {
  __builtin_amdgcn_global_load_lds(
      reinterpret_cast<const __attribute__((address_space(1))) uint32_t*>(
          reinterpret_cast<uintptr_t>(src)),
      reinterpret_cast<__attribute__((address_space(3))) uint32_t*>(
          reinterpret_cast<uintptr_t>(lds_dst)),
      16, 0, 0);
}

// Kernel 2: one block = (batch, 8 rows), 256 threads. Thread (w,lane) owns
// cols {512w+4*lane+j} and {512w+256+4*lane+j}, j=0..3, for all 8 rows.
// GEMM: R13's ka/kb k-double-buffer, with ev=7 PEELED. Between the last k
// load (kb7, issued in ev=6) and ev=7's FMAs, G rows 0-4 are issued via
// global_load_lds (zero VGPR: cannot be sunk -- no destination register to
// save -- and cannot spill) into a wave-private 40KB-block LDS slab. Issue
// order is k-then-G, so the compiler's kb7-wait is a COUNTED vmcnt that
// retires kb7 while G keeps flying (R6/R7's bug was G-before-kb: every
// kb-wait drained G's 900cy). ev=7's FMAs hide most of G's latency; one
// manual vmcnt(0)+sched_barrier before the LDS reads (compiler can't see
// the gload_lds->ds_read dep) exposes only the remainder (~400cy vs R16's
// ~3600cy rolling). Rows 5-7 use R16's register path (24 regs, sinkable,
// minor). LDS ~45KB -> 3 blocks/CU (R6's 70KB -> 1-2 was the killer).
__global__ __launch_bounds__(256, 2) void attn_kernel(
    const float* __restrict__ G,
    const float* __restrict__ q_ws, const float* __restrict__ kt_ws,
    float* __restrict__ out) {
  const int tid = threadIdx.x;
  const int b = blockIdx.y;
  const int r0 = blockIdx.x * 8;
  const int w = tid >> 6, lane = tid & 63;

  __shared__ float g_lds[4][5][512];  // 40 KB: wave-private G rows 0-4
  __shared__ float q_lds[4][256];     // wave-private q tile copies
  __shared__ float red[4][8];

  // ---- wave-private q copy (8 rows x 32 = 256 contiguous floats) ----
  {
    const float* qb = q_ws + ((size_t)b * NN + r0) * QK;
    *(float4*)&q_lds[w][4 * lane] = *(const float4*)&qb[4 * lane];
  }

  // ---- GEMM evs 0-6: acc[r][j] = q[r0+r] . k[col(w,lane,j)] ----
  float acc[8][8];
#pragma unroll
  for (int r = 0; r < 8; ++r)
#pragma unroll
    for (int j = 0; j < 8; ++j) acc[r][j] = 0.f;

  const float4* kt =
      (const float4*)kt_ws + (size_t)(b * 4 + w) * 4096 + lane;

  float4 ka[8], kb[8];
#pragma unroll
  for (int j = 0; j < 8; ++j) ka[j] = kt[j * 64];  // ev=0, lane-coalesced

#pragma unroll
  for (int ev = 0; ev < 7; ++ev) {
#pragma unroll
    for (int j = 0; j < 8; ++j) kb[j] = kt[((ev + 1) * 8 + j) * 64];
#pragma unroll
    for (int r = 0; r < 8; ++r) {
      float q4[4];
      *(float4*)q4 = *(const float4*)&q_lds[w][r * 32 + ev * 4];  // broadcast
#pragma unroll
      for (int j = 0; j < 8; ++j) {
        acc[r][j] = fmaf(q4[0], ka[j].x, acc[r][j]);
        acc[r][j] = fmaf(q4[1], ka[j].y, acc[r][j]);
        acc[r][j] = fmaf(q4[2], ka[j].z, acc[r][j]);
        acc[r][j] = fmaf(q4[3], ka[j].w, acc[r][j]);
      }
    }
#pragma unroll
    for (int j = 0; j < 8; ++j) ka[j] = kb[j];  // renamed away by unroll
  }
  // ka now holds ev=7's k (loaded during ev=6 iteration -> oldest VMEM).

  __builtin_amdgcn_sched_barrier(0);  // G issue stays AFTER all k loads

  // ---- issue G rows 0-4 -> wave-private LDS (10 async loads, 0 regs) ----
  const float* gb = G + ((size_t)b * NN + r0) * NN + 512 * w + 4 * lane;
#pragma unroll
  for (int r = 0; r < 5; ++r) {
    gload_lds16(gb + (size_t)r * NN, &g_lds[w][r][0]);
    gload_lds16(gb + (size_t)r * NN + 256, &g_lds[w][r][256]);
  }
  // ---- rows 5-7 -> registers (R16 path; sinkable, minor) ----
  f32x4 g5[3][2];
#pragma unroll
  for (int r = 0; r < 3; ++r) {
    g5[r][0] = *(const f32x4*)(gb + (size_t)(5 + r) * NN);
    g5[r][1] = *(const f32x4*)(gb + (size_t)(5 + r) * NN + 256);
  }
  __builtin_amdgcn_sched_barrier(0);  // loads stay above ev=7's FMAs

  // ---- ev=7 FMAs (hide G latency; kb7-wait is counted, G keeps flying) ----
#pragma unroll
  for (int r = 0; r < 8; ++r) {
    float q4[4];
    *(float4*)q4 = *(const float4*)&q_lds[w][r * 32 + 28];
#pragma unroll
    for (int j = 0; j < 8; ++j) {
      acc[r][j] = fmaf(q4[0], ka[j].x, acc[r][j]);
      acc[r][j] = fmaf(q4[1], ka[j].y, acc[r][j]);
      acc[r][j] = fmaf(q4[2], ka[j].z, acc[r][j]);
      acc[r][j] = fmaf(q4[3], ka[j].w, acc[r][j]);
    }
  }

  // ---- all G landed (compiler can't see gload_lds->ds_read dep) ----
  asm volatile("s_waitcnt vmcnt(0)" ::: "memory");
  __builtin_amdgcn_sched_barrier(0);

  float rsum[8];
#pragma unroll
  for (int r = 0; r < 8; ++r) {
    float gg[8];
    if (r < 5) {
      *(float4*)&gg[0] = *(const float4*)&g_lds[w][r][4 * lane];
      *(float4*)&gg[4] = *(const float4*)&g_lds[w][r][256 + 4 * lane];
    } else {
      *(f32x4*)&gg[0] = g5[r - 5][0];
      *(f32x4*)&gg[4] = g5[r - 5][1];
    }
    float sum = 0.f;
#pragma unroll
    for (int j = 0; j < 8; ++j) {
      float v = acc[r][j];
      v = v * v * gg[j];
      acc[r][j] = v;
      sum += v;
    }
#pragma unroll
    for (int off = 32; off >= 1; off >>= 1) sum += __shfl_xor(sum, off, 64);
    rsum[r] = sum;
  }

  // ---- cross-wave reduce ----
  if ((tid & 63) == 0) {
#pragma unroll
    for (int r = 0; r < 8; ++r) red[w][r] = rsum[r];
  }
  __syncthreads();

  float inv[8];
#pragma unroll
  for (int r = 0; r < 8; ++r) {
    float total = red[0][r] + red[1][r] + red[2][r] + red[3][r];
    inv[r] = 1.0f / (total + 1e-6f);
  }

  // ---- scale + coalesced non-temporal store ----
  float* ob = out + ((size_t)b * NN + r0) * NN + 512 * w + 4 * lane;
#pragma unroll
  for (int r = 0; r < 8; ++r) {
    f32x4 o0, o1;
    o0.x = acc[r][0] * inv[r]; o0.y = acc[r][1] * inv[r];
    o0.z = acc[r][2] * inv[r]; o0.w = acc[r][3] * inv[r];
    o1.x = acc[r][4] * inv[r]; o1.y = acc[r][5] * inv[r];
    o1.z = acc[r][6] * inv[r]; o1.w = acc[r][7] * inv[r];
    __builtin_nontemporal_store(o0, (f32x4*)(ob + (size_t)r * NN));
    __builtin_nontemporal_store(o1, (f32x4*)(ob + (size_t)r * NN + 256));
  }
}

extern "C" void kernel_launch(void* const* d_in, const int* in_sizes, int n_in,
                              void* d_out, int out_size, void* d_ws, size_t ws_size,
                              hipStream_t stream) {
  const float* s  = (const float*)d_in[0];
  const float* G  = (const float*)d_in[1];
  const float* Wq = (const float*)d_in[2];
  const float* Wk = (const float*)d_in[3];
  float* out = (float*)d_out;

  float* q_ws  = (float*)d_ws;                       // B*N*QK floats = 2 MB
  float* kt_ws = q_ws + (size_t)BB * NN * QK;        // another 2 MB

  qk_kernel<<<(BB * NN * QK) / 256, 256, 0, stream>>>(s, Wq, Wk, q_ws, kt_ws);

  dim3 grid(NN / 8, BB);
  attn_kernel<<<grid, 256, 0, stream>>>(G, q_ws, kt_ws, out);
}

// Round 22
// 62.574 us; speedup vs baseline: 1.1280x; 1.1280x over previous
//
#include <hip/hip_runtime.h>
#include <stdint.h>

#define BB 8
#define NN 2048
#define IND 10
#define QK 32

typedef float f32x4 __attribute__((ext_vector_type(4)));

// Kernel 1: q[b][n][qd] = sum_d s[b,n,d]*Wq[qd,d]; k likewise.
// kt permuted for kernel 2's read: attn thread (wave w, lane i) owns cols
//   {512w + 4i + j : j=0..3} and {512w + 256 + 4i + j : j=0..3}.
// kt float4 index: (b*4+w)*4096 + (ev*8+jc)*64 + i, component c (qd=4ev+c).
__global__ __launch_bounds__(256) void qk_kernel(
    const float* __restrict__ s,
    const float* __restrict__ Wq, const float* __restrict__ Wk,
    float* __restrict__ q_ws, float* __restrict__ kt_ws) {
  int t = blockIdx.x * 256 + threadIdx.x;      // 0 .. B*N*QK-1 (exact)
  int b  = t >> 16;                            // N*QK = 65536
  int n  = (t >> 5) & (NN - 1);
  int qd = t & 31;
  const float* srow = s + (size_t)(b * NN + n) * IND;
  float acq = 0.f, ack = 0.f;
#pragma unroll
  for (int d = 0; d < IND; ++d) {
    float sv = srow[d];
    acq = fmaf(sv, Wq[qd * IND + d], acq);
    ack = fmaf(sv, Wk[qd * IND + d], ack);
  }
  q_ws[(size_t)(b * NN + n) * QK + qd] = acq;
  int w  = n >> 9;                 // wave (512 cols each)
  int m  = n & 511;
  int i  = (m & 255) >> 2;         // lane
  int jc = ((m < 256) ? 0 : 4) + (m & 3);
  int ev = qd >> 2, c = qd & 3;
  kt_ws[(((size_t)(b * 4 + w) * 4096) + (ev * 8 + jc) * 64 + i) * 4 + c] = ack;
}

// Kernel 2 (R16, the empirical optimum of the 21-round search):
// one block = (batch, 8 rows), 256 threads. Thread (w,lane) owns cols
// {512w+4*lane+j} and {512w+256+4*lane+j}, j=0..3, for all 8 rows.
// GEMM: ka/kb k-double-buffer (R13, +10%). Epilogue: G prefetch into
// registers with one post-load fence; compiler may hoist the issue into the
// GEMM tail. launch_bounds(256,2) for the 256-VGPR cap. NT stores keep the
// output stream from evicting G/kt from L3.
// Closed-out alternatives (all regressed on HW): asm-pinned prefetch (R17:
// spill), sched_group_barrier (R19: dissolved), LDS G-staging in any form
// (R6/R7/R12/R21: occupancy loss and/or spill), NT G loads (R15), 4-row /
// 16-row / 8-wave tiles (R10/R11/R18).
__global__ __launch_bounds__(256, 2) void attn_kernel(
    const float* __restrict__ G,
    const float* __restrict__ q_ws, const float* __restrict__ kt_ws,
    float* __restrict__ out) {
  const int tid = threadIdx.x;
  const int b = blockIdx.y;
  const int r0 = blockIdx.x * 8;
  const int w = tid >> 6, lane = tid & 63;

  __shared__ float q_lds[4][256];  // wave-private q tile copies (1 KB/wave)
  __shared__ float red[4][8];

  // ---- wave-private q copy (8 rows x 32 = 256 contiguous floats) ----
  {
    const float* qb = q_ws + ((size_t)b * NN + r0) * QK;
    *(float4*)&q_lds[w][4 * lane] = *(const float4*)&qb[4 * lane];
  }

  // ---- GEMM: acc[r][j] = q[r0+r] . k[col(w,lane,j)] ----
  float acc[8][8];
#pragma unroll
  for (int r = 0; r < 8; ++r)
#pragma unroll
    for (int j = 0; j < 8; ++j) acc[r][j] = 0.f;

  const float4* kt =
      (const float4*)kt_ws + (size_t)(b * 4 + w) * 4096 + lane;

  float4 ka[8], kb[8];
#pragma unroll
  for (int j = 0; j < 8; ++j) ka[j] = kt[j * 64];  // ev=0, lane-coalesced

#pragma unroll
  for (int ev = 0; ev < 8; ++ev) {
    if (ev < 7) {
#pragma unroll
      for (int j = 0; j < 8; ++j) kb[j] = kt[((ev + 1) * 8 + j) * 64];
    }
#pragma unroll
    for (int r = 0; r < 8; ++r) {
      float q4[4];
      *(float4*)q4 = *(const float4*)&q_lds[w][r * 32 + ev * 4];  // broadcast
#pragma unroll
      for (int j = 0; j < 8; ++j) {
        acc[r][j] = fmaf(q4[0], ka[j].x, acc[r][j]);
        acc[r][j] = fmaf(q4[1], ka[j].y, acc[r][j]);
        acc[r][j] = fmaf(q4[2], ka[j].z, acc[r][j]);
        acc[r][j] = fmaf(q4[3], ka[j].w, acc[r][j]);
      }
    }
#pragma unroll
    for (int j = 0; j < 8; ++j) ka[j] = kb[j];  // renamed away by unroll
  }

  // ---- epilogue: prefetch ALL G into registers (compiler may hoist the
  //      issue into the GEMM tail; loads are after the last k-load in
  //      program order, so k vmcnt-waits never count them) ----
  const float* gb = G + ((size_t)b * NN + r0) * NN + 512 * w + 4 * lane;
  float4 g0[8], g1[8];
#pragma unroll
  for (int r = 0; r < 8; ++r) {
    g0[r] = *(const float4*)(gb + (size_t)r * NN);
    g1[r] = *(const float4*)(gb + (size_t)r * NN + 256);
  }
  __builtin_amdgcn_sched_barrier(0);  // math stays below the loads

  float rsum[8];
#pragma unroll
  for (int r = 0; r < 8; ++r) {
    float gg[8];
    *(float4*)&gg[0] = g0[r];
    *(float4*)&gg[4] = g1[r];
    float sum = 0.f;
#pragma unroll
    for (int j = 0; j < 8; ++j) {
      float v = acc[r][j];
      v = v * v * gg[j];
      acc[r][j] = v;
      sum += v;
    }
#pragma unroll
    for (int off = 32; off >= 1; off >>= 1) sum += __shfl_xor(sum, off, 64);
    rsum[r] = sum;
  }

  // ---- cross-wave reduce ----
  if ((tid & 63) == 0) {
#pragma unroll
    for (int r = 0; r < 8; ++r) red[w][r] = rsum[r];
  }
  __syncthreads();

  float inv[8];
#pragma unroll
  for (int r = 0; r < 8; ++r) {
    float total = red[0][r] + red[1][r] + red[2][r] + red[3][r];
    inv[r] = 1.0f / (total + 1e-6f);
  }

  // ---- scale + coalesced non-temporal store ----
  float* ob = out + ((size_t)b * NN + r0) * NN + 512 * w + 4 * lane;
#pragma unroll
  for (int r = 0; r < 8; ++r) {
    f32x4 o0, o1;
    o0.x = acc[r][0] * inv[r]; o0.y = acc[r][1] * inv[r];
    o0.z = acc[r][2] * inv[r]; o0.w = acc[r][3] * inv[r];
    o1.x = acc[r][4] * inv[r]; o1.y = acc[r][5] * inv[r];
    o1.z = acc[r][6] * inv[r]; o1.w = acc[r][7] * inv[r];
    __builtin_nontemporal_store(o0, (f32x4*)(ob + (size_t)r * NN));
    __builtin_nontemporal_store(o1, (f32x4*)(ob + (size_t)r * NN + 256));
  }
}

extern "C" void kernel_launch(void* const* d_in, const int* in_sizes, int n_in,
                              void* d_out, int out_size, void* d_ws, size_t ws_size,
                              hipStream_t stream) {
  const float* s  = (const float*)d_in[0];
  const float* G  = (const float*)d_in[1];
  const float* Wq = (const float*)d_in[2];
  const float* Wk = (const float*)d_in[3];
  float* out = (float*)d_out;

  float* q_ws  = (float*)d_ws;                       // B*N*QK floats = 2 MB
  float* kt_ws = q_ws + (size_t)BB * NN * QK;        // another 2 MB

  qk_kernel<<<(BB * NN * QK) / 256, 256, 0, stream>>>(s, Wq, Wk, q_ws, kt_ws);

  dim3 grid(NN / 8, BB);
  attn_kernel<<<grid, 256, 0, stream>>>(G, q_ws, kt_ws, out);
}